// Round 9
// baseline (775.127 us; speedup 1.0000x reference)
//
#include <hip/hip_runtime.h>
#include <hip/hip_bf16.h>
#include <stdint.h>

// Problem constants (match setup_inputs)
#define M_ROWS 100352   // 2048 * 49
#define C_DIM  512
#define QKV_N  1536
#define NH     16
#define HD     32
#define NWIN   49       // window tokens (7*7)
#define NMASK  64

typedef __attribute__((ext_vector_type(4)))  float        f32x4;
typedef __attribute__((ext_vector_type(16))) float        f32x16;
typedef __attribute__((ext_vector_type(8)))  short        bf16x8;
typedef __attribute__((ext_vector_type(4)))  unsigned int u32x4;

static __device__ __forceinline__ unsigned short f32_to_bf16(float f) {
  union { float f; unsigned int u; } v; v.f = f;
  unsigned int u = v.u;
  return (unsigned short)((u + 0x7FFFu + ((u >> 16) & 1u)) >> 16);  // RNE
}

// ---------------------------------------------------------------- frag layout
// Element (row m, col k) of a row-major [R][512] bf16 matrix lives at ushort
// address ((m>>5)*32 + (k>>4))*512 + ((m&31) + 32*((k>>3)&1))*8 + (k&7).
// One chunk (32 rows x 16 k) = 64 lanes x 16 B contiguous -> MFMA operand
// loads from global are single coalesced global_load_dwordx4 per lane:
// lane holds row = 32-blk + (lane&31), k = 16*ks + 8*(lane>>5) + {0..7}.
// Both GEMM operands use the same transform, so any within-16-k permutation
// cancels in the dot product.

// ------------------------------------------------- k_cvtf: x f32 -> A-frag
// One wave per row: lane reads x[m][lane*8..+7] (32 B coalesced), writes one
// 16 B chunk slot.  Blocks of 4 consecutive rows complete 64 B lines.
__global__ __launch_bounds__(256) void k_cvtf(const float* __restrict__ in,
                                              unsigned short* __restrict__ out) {
  const int m = blockIdx.x * 4 + (threadIdx.x >> 6);
  const int lane = threadIdx.x & 63;
  const float4 v0 = *(const float4*)(in + (size_t)m * C_DIM + lane * 8);
  const float4 v1 = *(const float4*)(in + (size_t)m * C_DIM + lane * 8 + 4);
  u32x4 st;
  st[0] = (unsigned int)f32_to_bf16(v0.x) | ((unsigned int)f32_to_bf16(v0.y) << 16);
  st[1] = (unsigned int)f32_to_bf16(v0.z) | ((unsigned int)f32_to_bf16(v0.w) << 16);
  st[2] = (unsigned int)f32_to_bf16(v1.x) | ((unsigned int)f32_to_bf16(v1.y) << 16);
  st[3] = (unsigned int)f32_to_bf16(v1.z) | ((unsigned int)f32_to_bf16(v1.w) << 16);
  // k8 = lane: ks = lane>>1, half = lane&1
  const size_t addr = ((size_t)(m >> 5) * 32 + (lane >> 1)) * 512 +
                      ((m & 31) + 32 * (lane & 1)) * 8;
  *(u32x4*)(out + addr) = st;
}

// ------------------------------------------- transpose + convert weights
// in: K x N f32 (row-major), out: N x K bf16 (row-major) == B^T
__global__ void k_transpose_cvt(const float* __restrict__ in, unsigned short* __restrict__ out,
                                int K, int N) {
  __shared__ float t[32][33];
  const int n0 = blockIdx.x * 32, k0 = blockIdx.y * 32;
  const int tx = threadIdx.x & 31, ty = threadIdx.x >> 5;  // 32 x 8
#pragma unroll
  for (int rr = 0; rr < 32; rr += 8)
    t[ty + rr][tx] = in[(size_t)(k0 + ty + rr) * N + n0 + tx];
  __syncthreads();
#pragma unroll
  for (int rr = 0; rr < 32; rr += 8)
    out[(size_t)(n0 + ty + rr) * K + k0 + tx] = f32_to_bf16(t[tx][ty + rr]);
}

// ---------------------------------------- k_tofrag: row-major bf16 -> frag
__global__ __launch_bounds__(256) void k_tofrag(const unsigned short* __restrict__ in,
                                                unsigned short* __restrict__ out) {
  const int m = blockIdx.x * 4 + (threadIdx.x >> 6);
  const int lane = threadIdx.x & 63;
  const u32x4 v = *(const u32x4*)(in + (size_t)m * C_DIM + lane * 8);
  const size_t addr = ((size_t)(m >> 5) * 32 + (lane >> 1)) * 512 +
                      ((m & 31) + 32 * (lane & 1)) * 8;
  *(u32x4*)(out + addr) = v;
}

// ----------------------------------------- fused bias+mask table (padded)
// bmt[w][h][i][j] (64x16x64x64 f32) = mask[w][i][j] + bias[h][i][j], -1e30 pad.
__global__ __launch_bounds__(256) void k_bm(const float* __restrict__ mask,
                                            const float* __restrict__ rel,
                                            float* __restrict__ bmt) {
  const int idx = blockIdx.x * 256 + threadIdx.x;   // w<<16 | h<<12 | i<<6 | j
  const int j = idx & 63, i = (idx >> 6) & 63, h = (idx >> 12) & 15, w = idx >> 16;
  float v = -1e30f;
  if (i < NWIN && j < NWIN) {
    const int rpi = ((j / 7) - (i / 7) + 6) * 13;
    v = mask[w * (NWIN * NWIN) + i * NWIN + j] + rel[rpi * NH + h];
  }
  bmt[idx] = v;
}

// ------------------------------------------------ GEMM (register streaming)
// C[M,N] = A[M,512] * BT[N,512]^T + bias[N], A/B in frag layout (above).
// 128x128 tile, 4 waves (2x2), 64x64/wave = 2x2 frags of 32x32x16 MFMA.
// NO LDS, NO barriers, NO asm: 32 unrolled k16-steps of 4 coalesced
// global_load_dwordx4 + 4 MFMA; compiler software-pipelines freely.
// B is L2-resident (<=1.5MB); A panels L2-local via bx-fastest XCD swizzle;
// same-wr wave pairs dedup A loads through L1.
// SWAPPED operands: acc[fm][fn] = mfma(b, a, acc) -> lane holds
// m = 32blk + (lane&31), n = 8q + 4*(lane>>5) + r (4 consecutive per q)
// -> packed 8B/16B C-stores.
template <int OUT_BF16>
__global__ __launch_bounds__(256, 3) void k_gemmf(const unsigned short* __restrict__ Af,
                                                  const unsigned short* __restrict__ Bf,
                                                  const float* __restrict__ bias,
                                                  void* __restrict__ Cout,
                                                  int M, int N) {
  const int lane = threadIdx.x & 63, wave = threadIdx.x >> 6;
  const int wr = wave >> 1, wc = wave & 1;
  const int l31 = lane & 31, lhi = lane >> 5;

  // bijective XCD swizzle (grid %8==0); bx fastest -> same-XCD neighbors
  // share the A panel (L2 reuse).
  const int nwg = gridDim.x, q8 = nwg >> 3;
  const int wg = (blockIdx.x & 7) * q8 + (blockIdx.x >> 3);
  const int gx = N >> 7;
  const int bx = wg % gx, by = wg / gx;
  const int m0 = by << 7, n0 = bx << 7;

  // frag-chunk base pointers (ushorts): ((rowblk*32 + ks)*64 + lane)*8
  const unsigned short* pa0 = Af + ((size_t)((m0 >> 5) + wr * 2 + 0) * 32 * 64 + lane) * 8;
  const unsigned short* pa1 = Af + ((size_t)((m0 >> 5) + wr * 2 + 1) * 32 * 64 + lane) * 8;
  const unsigned short* pb0 = Bf + ((size_t)((n0 >> 5) + wc * 2 + 0) * 32 * 64 + lane) * 8;
  const unsigned short* pb1 = Bf + ((size_t)((n0 >> 5) + wc * 2 + 1) * 32 * 64 + lane) * 8;

  f32x16 acc00 = {}, acc01 = {}, acc10 = {}, acc11 = {};

#pragma unroll
  for (int ks = 0; ks < 32; ++ks) {
    const bf16x8 a0 = *(const bf16x8*)(pa0 + ks * 512);
    const bf16x8 a1 = *(const bf16x8*)(pa1 + ks * 512);
    const bf16x8 b0 = *(const bf16x8*)(pb0 + ks * 512);
    const bf16x8 b1 = *(const bf16x8*)(pb1 + ks * 512);
    acc00 = __builtin_amdgcn_mfma_f32_32x32x16_bf16(b0, a0, acc00, 0, 0, 0);
    acc01 = __builtin_amdgcn_mfma_f32_32x32x16_bf16(b1, a0, acc01, 0, 0, 0);
    acc10 = __builtin_amdgcn_mfma_f32_32x32x16_bf16(b0, a1, acc10, 0, 0, 0);
    acc11 = __builtin_amdgcn_mfma_f32_32x32x16_bf16(b1, a1, acc11, 0, 0, 0);
  }

  // epilogue: rows m = m0+wr*64+fm*32+l31; cols n = n0+wc*64+fn*32+8q+4lhi+{0..3}
  const f32x16* accp[2][2] = {{&acc00, &acc01}, {&acc10, &acc11}};
#pragma unroll
  for (int fm = 0; fm < 2; ++fm) {
    const size_t row = (size_t)(m0 + wr * 64 + fm * 32 + l31);
#pragma unroll
    for (int fn = 0; fn < 2; ++fn) {
      const int colb = n0 + wc * 64 + fn * 32 + 4 * lhi;
      const f32x16& a = *accp[fm][fn];
#pragma unroll
      for (int q = 0; q < 4; ++q) {
        const int n4 = colb + 8 * q;
        const f32x4 b4 = *(const f32x4*)(bias + n4);
        const float v0 = a[4 * q + 0] + b4[0];
        const float v1 = a[4 * q + 1] + b4[1];
        const float v2 = a[4 * q + 2] + b4[2];
        const float v3 = a[4 * q + 3] + b4[3];
        if (OUT_BF16) {
          uint2 st;
          st.x = (unsigned int)f32_to_bf16(v0) | ((unsigned int)f32_to_bf16(v1) << 16);
          st.y = (unsigned int)f32_to_bf16(v2) | ((unsigned int)f32_to_bf16(v3) << 16);
          *(uint2*)((unsigned short*)Cout + row * N + n4) = st;
        } else {
          f32x4 st = {v0, v1, v2, v3};
          *(f32x4*)((float*)Cout + row * N + n4) = st;
        }
      }
    }
  }
}

// ------------------------------------------------------------- attention
// 4 waves/block, one (b,h) per wave, zero barriers (waves independent).
// Output written in FRAG layout (consumed by the proj k_gemmf).
__global__ __launch_bounds__(256) void k_attn(const unsigned short* __restrict__ qkv,
                                              const float* __restrict__ bmt,
                                              unsigned short* __restrict__ aout) {
  const int wave = threadIdx.x >> 6, lane = threadIdx.x & 63;
  const int lr = lane & 15, lg = lane >> 4;
  const int idx = blockIdx.x * 4 + wave;
  const int b = idx >> 4, h = idx & 15, w = b & 63;

  __shared__ __align__(16) unsigned short Pl[4][2048];  // [32 rows][64] swizzled
  __shared__ __align__(16) unsigned short Vt[4][2112];  // V^T, stride 66
  unsigned short* pl = Pl[wave];
  unsigned short* vt = Vt[wave];

  const unsigned short* qp = qkv + (size_t)b * NWIN * QKV_N + h * HD;
  const unsigned short* kp = qp + C_DIM;
  const unsigned short* vp = qp + 2 * C_DIM;

  bf16x8 kf[4], qf[4];
#pragma unroll
  for (int t = 0; t < 4; ++t) {
    kf[t] = *(const bf16x8*)(kp + (size_t)(t * 16 + lr) * QKV_N + lg * 8);
    qf[t] = *(const bf16x8*)(qp + (size_t)(t * 16 + lr) * QKV_N + lg * 8);
  }

  const u32x4 zv = {0u, 0u, 0u, 0u};
#pragma unroll
  for (int c0 = 0; c0 < 4; ++c0) {
    const int c = c0 * 64 + lane;
    const int key = c >> 2, d0 = (c & 3) << 3;
    union { u32x4 v; unsigned short s[8]; } tmp;
    tmp.v = (key < NWIN) ? *(const u32x4*)(vp + (size_t)key * QKV_N + d0) : zv;
#pragma unroll
    for (int jj = 0; jj < 8; ++jj) vt[(d0 + jj) * 66 + key] = tmp.s[jj];
  }

  const f32x4 fz = {0.f, 0.f, 0.f, 0.f};
  f32x4 s[4][4];  // [mi = j-frag][ni = i-frag]
#pragma unroll
  for (int mi = 0; mi < 4; ++mi)
#pragma unroll
    for (int ni = 0; ni < 4; ++ni) s[mi][ni] = fz;
#pragma unroll
  for (int mi = 0; mi < 4; ++mi)
#pragma unroll
    for (int ni = 0; ni < 4; ++ni)
      s[mi][ni] = __builtin_amdgcn_mfma_f32_16x16x32_bf16(kf[mi], qf[ni], s[mi][ni], 0, 0, 0);

  union VU { unsigned int u[4]; bf16x8 v; };
  VU vfr[2][2];  // [nj][ks]
#pragma unroll
  for (int nj = 0; nj < 2; ++nj)
#pragma unroll
    for (int ks = 0; ks < 2; ++ks) {
      const int base = ((16 * nj + lr) * 66 + 32 * ks + 8 * lg) >> 1;
#pragma unroll
      for (int u = 0; u < 4; ++u) vfr[nj][ks].u[u] = ((const unsigned int*)vt)[base + u];
    }

  const float scale = 0.1767766952966369f;  // 32^-0.5
  const float* tbl = bmt + ((size_t)(w * NH + h) << 12);

  f32x4 o[4][2];
#pragma unroll
  for (int qi = 0; qi < 4; ++qi)
#pragma unroll
    for (int nj = 0; nj < 2; ++nj) o[qi][nj] = fz;

#pragma unroll
  for (int ni = 0; ni < 4; ++ni) {
    float v[16];
    float mx = -3e38f;
#pragma unroll
    for (int mi = 0; mi < 4; ++mi) {
      const f32x4 t4 = *(const f32x4*)(tbl + (16 * ni + lr) * 64 + 16 * mi + 4 * lg);
#pragma unroll
      for (int r = 0; r < 4; ++r) {
        v[mi * 4 + r] = fmaf(s[mi][ni][r], scale, t4[r]);
        mx = fmaxf(mx, v[mi * 4 + r]);
      }
    }
    mx = fmaxf(mx, __shfl_xor(mx, 16));
    mx = fmaxf(mx, __shfl_xor(mx, 32));
    float sum = 0.f;
#pragma unroll
    for (int t = 0; t < 16; ++t) {
      v[t] = __expf(v[t] - mx);
      sum += v[t];
    }
    sum += __shfl_xor(sum, 16);
    sum += __shfl_xor(sum, 32);
    const float inv = __builtin_amdgcn_rcpf(sum);

    const int ip = 16 * (ni & 1) + lr;
#pragma unroll
    for (int mi = 0; mi < 4; ++mi) {
      const unsigned int lo = (unsigned int)f32_to_bf16(v[mi * 4 + 0] * inv) |
                              ((unsigned int)f32_to_bf16(v[mi * 4 + 1] * inv) << 16);
      const unsigned int hi = (unsigned int)f32_to_bf16(v[mi * 4 + 2] * inv) |
                              ((unsigned int)f32_to_bf16(v[mi * 4 + 3] * inv) << 16);
      const int byteoff = 32 * mi + 8 * lg;
      const int sw = byteoff ^ ((ip & 7) << 4);
      uint2 w2; w2.x = lo; w2.y = hi;
      *(uint2*)((char*)pl + ip * 128 + sw) = w2;
    }

    if (ni & 1) {
      asm volatile("s_waitcnt lgkmcnt(0)" ::: "memory");
      __builtin_amdgcn_sched_barrier(0);
      const int half = ni >> 1;
#pragma unroll
      for (int q2 = 0; q2 < 2; ++q2) {
        const int qi = half * 2 + q2;
        const int ipr = 16 * q2 + lr;
#pragma unroll
        for (int ks = 0; ks < 2; ++ks) {
          const int bo = 64 * ks + 16 * lg;
          const int swr = bo ^ ((ipr & 7) << 4);
          const bf16x8 pa = *(const bf16x8*)((const char*)pl + ipr * 128 + swr);
#pragma unroll
          for (int nj = 0; nj < 2; ++nj)
            o[qi][nj] = __builtin_amdgcn_mfma_f32_16x16x32_bf16(pa, vfr[nj][ks].v, o[qi][nj], 0, 0, 0);
        }
      }
    }
  }

  // store O in FRAG layout: element (R = b*49+i, k = h*32 + nj*16 + lr)
  // -> aout[((R>>5)*32 + h*2+nj)*512 + ((R&31) + 32*(lr>>3))*8 + (lr&7)]
  const int R_base = b * NWIN;
  const int ksub = ((lr >> 3) * 32 + (lr & 7));  // 32*(k>>3&1)*... partial
#pragma unroll
  for (int qi = 0; qi < 4; ++qi)
#pragma unroll
    for (int r = 0; r < 4; ++r) {
      const int i = 16 * qi + 4 * lg + r;
      if (i < NWIN) {
        const int R = R_base + i;
        const size_t base = ((size_t)(R >> 5) * 32 + h * 2) * 512 +
                            ((R & 31) + 32 * (lr >> 3)) * 8 + (lr & 7);
#pragma unroll
        for (int nj = 0; nj < 2; ++nj)
          aout[base + nj * 512] = f32_to_bf16(o[qi][nj][r]);
      }
    }
  (void)ksub;
}

// ---------------------------------------------------------------- launch
static const size_t SZ_QKV = (size_t)M_ROWS * QKV_N * 2;   // 308 MB
static const size_t SZ_XA  = (size_t)M_ROWS * C_DIM * 2;   // 103 MB
static const size_t SZ_WQ  = (size_t)QKV_N * C_DIM * 2;    // 1.5 MB
static const size_t SZ_WP  = (size_t)C_DIM * C_DIM * 2;    // 0.5 MB
static const size_t OFF_QKV = 0;
static const size_t OFF_XA  = OFF_QKV + SZ_QKV;   // x-frag, later attn-out-frag
static const size_t OFF_WQT = OFF_XA + SZ_XA;     // wq B^T row-major (temp)
static const size_t OFF_WPT = OFF_WQT + SZ_WQ;
static const size_t OFF_WQF = OFF_WPT + SZ_WP;    // wq frag
static const size_t OFF_WPF = OFF_WQF + SZ_WQ;

extern "C" void kernel_launch(void* const* d_in, const int* in_sizes, int n_in,
                              void* d_out, int out_size, void* d_ws, size_t ws_size,
                              hipStream_t stream) {
  const float* x      = (const float*)d_in[0];
  const float* mask   = (const float*)d_in[1];
  const float* qkv_w  = (const float*)d_in[2];
  const float* qkv_b  = (const float*)d_in[3];
  const float* proj_w = (const float*)d_in[4];
  const float* proj_b = (const float*)d_in[5];
  const float* rel    = (const float*)d_in[6];
  float* out = (float*)d_out;

  char* ws = (char*)d_ws;
  unsigned short* qkvb = (unsigned short*)(ws + OFF_QKV);
  unsigned short* xaf  = (unsigned short*)(ws + OFF_XA);
  unsigned short* wqT  = (unsigned short*)(ws + OFF_WQT);
  unsigned short* wpT  = (unsigned short*)(ws + OFF_WPT);
  unsigned short* wqF  = (unsigned short*)(ws + OFF_WQF);
  unsigned short* wpF  = (unsigned short*)(ws + OFF_WPF);
  // bmt (16.78 MB) in d_out scratch: fully consumed by k_attn before final GEMM.
  float* bmt = (float*)d_out;

  k_cvtf<<<M_ROWS / 4, 256, 0, stream>>>(x, xaf);
  k_transpose_cvt<<<dim3(QKV_N / 32, C_DIM / 32), 256, 0, stream>>>(qkv_w, wqT, C_DIM, QKV_N);
  k_transpose_cvt<<<dim3(C_DIM / 32, C_DIM / 32), 256, 0, stream>>>(proj_w, wpT, C_DIM, C_DIM);
  k_tofrag<<<QKV_N / 4, 256, 0, stream>>>(wqT, wqF);
  k_tofrag<<<C_DIM / 4, 256, 0, stream>>>(wpT, wpF);
  k_bm<<<(NMASK * NH * 64 * 64) / 256, 256, 0, stream>>>(mask, rel, bmt);

  // qkv = x @ qkv_w + qkv_b  (bf16 row-major out), grid 784*12 = 9408 (%8==0)
  k_gemmf<1><<<(M_ROWS / 128) * (QKV_N / 128), 256, 0, stream>>>(
      xaf, wqF, qkv_b, qkvb, M_ROWS, QKV_N);

  // attention -> attn-out FRAG layout (reuses xaf region)
  k_attn<<<2048 * NH / 4, 256, 0, stream>>>(qkvb, bmt, xaf);

  // out = attn_out @ proj_w + proj_b  (f32 out), grid 784*4 = 3136 (%8==0)
  k_gemmf<0><<<(M_ROWS / 128) * (C_DIM / 128), 256, 0, stream>>>(
      xaf, wpF, proj_b, out, M_ROWS, C_DIM);
}